// Round 6
// baseline (2227.644 us; speedup 1.0000x reference)
//
#include <hip/hip_runtime.h>
#include <hip/hip_fp16.h>
#include <cstdint>
#include <cstddef>

#define E_HID 256
#define R_HID 128
#define NREL  1000
#define EPSF  1e-16f
#define NB    512                 // blocks for edge passes (k2/k4)
#define CH_BITS 12
#define NCH   13                  // ceil(50000/4096) node chunks
#define RT    16                  // relations per tile
#define NRT   63                  // ceil(1000/16)
#define NBIN  (NRT * NCH)         // 819 bins per table
#define REP   16                  // edge-slice replicas per (table, rtile)
#define QTOT  (REP * 4)           // wave-slices per (table, rtile)
#define G5    (2 * NRT * REP)     // 2016 blocks (~8/CU)

typedef _Float16 f16x8 __attribute__((ext_vector_type(8)));
typedef float f32x4 __attribute__((ext_vector_type(4)));

struct alignas(16) h8 { __half2 a, b, c, d; };

// ================= K0: WcT[c][k] = fp16 of (c<128 ? Wh[k][c] : Wt[k][c-128])
__global__ __launch_bounds__(256) void k0_prep(
    const float* __restrict__ Wh, const float* __restrict__ Wt,
    __half* __restrict__ WcT)
{
  const int k = blockIdx.x;
  const int c = threadIdx.x;
  const float v = (c < R_HID) ? Wh[(size_t)k * R_HID + c]
                              : Wt[(size_t)k * R_HID + (c - R_HID)];
  WcT[(size_t)c * E_HID + k] = __float2half(v);
}

// ================= K1: MFMA fp16 GEMM (validated R3/R4) =====================
__global__ __launch_bounds__(256) void k1_gemm(
    const float* __restrict__ xe, const __half* __restrict__ WcT,
    const float* __restrict__ ah1, const float* __restrict__ ah2,
    const float* __restrict__ at1, const float* __restrict__ at2,
    __half* __restrict__ xhH, __half* __restrict__ xtH,
    float* __restrict__ sh1, float* __restrict__ sh2,
    float* __restrict__ st1, float* __restrict__ st2, int N)
{
  __shared__ __half As[128 * 32];
  __shared__ __half Bs[128 * 32];
  __shared__ float sA[2][128];
  __shared__ float sB[2][128];

  const int tid  = threadIdx.x;
  const int lane = tid & 63;
  const int wid  = tid >> 6;
  const int wr = wid >> 1, wc = wid & 1;
  const int nbm = (N + 127) >> 7;
  const int mb = blockIdx.x % nbm;
  const int cb = blockIdx.x / nbm;
  const int n0 = mb * 128;

  f32x4 acc[4][4];
  #pragma unroll
  for (int m = 0; m < 4; ++m)
    #pragma unroll
    for (int n = 0; n < 4; ++n) acc[m][n] = (f32x4){0.f, 0.f, 0.f, 0.f};

  const int arow = tid >> 1, ah = tid & 1;
  const bool aok = (n0 + arow) < N;
  const float*  xsrc = xe + (size_t)(n0 + arow) * E_HID + ah * 16;
  const __half* bsrc = WcT + ((size_t)(cb * 128 + arow) << 8) + ah * 16;
  __half* Aw = &As[arow * 32 + ah * 16];
  __half* Bw = &Bs[arow * 32 + ah * 16];

  const int fr = lane & 15, fq = lane >> 4;

  for (int kt = 0; kt < 8; ++kt) {
    __syncthreads();
    float4 v0 = make_float4(0,0,0,0), v1 = v0, v2 = v0, v3 = v0;
    if (aok) {
      const float* s = xsrc + kt * 32;
      v0 = *(const float4*)(s);     v1 = *(const float4*)(s + 4);
      v2 = *(const float4*)(s + 8); v3 = *(const float4*)(s + 12);
    }
    h8 p0, p1;
    p0.a = __floats2half2_rn(v0.x, v0.y); p0.b = __floats2half2_rn(v0.z, v0.w);
    p0.c = __floats2half2_rn(v1.x, v1.y); p0.d = __floats2half2_rn(v1.z, v1.w);
    p1.a = __floats2half2_rn(v2.x, v2.y); p1.b = __floats2half2_rn(v2.z, v2.w);
    p1.c = __floats2half2_rn(v3.x, v3.y); p1.d = __floats2half2_rn(v3.z, v3.w);
    *(h8*)(Aw) = p0; *(h8*)(Aw + 8) = p1;
    float4 b0 = *(const float4*)(bsrc + kt * 32);
    float4 b1 = *(const float4*)(bsrc + kt * 32 + 8);
    *(float4*)(Bw) = b0; *(float4*)(Bw + 8) = b1;
    __syncthreads();
    f16x8 aF[4], bF[4];
    #pragma unroll
    for (int m = 0; m < 4; ++m)
      aF[m] = *(const f16x8*)&As[(wr * 64 + m * 16 + fr) * 32 + fq * 8];
    #pragma unroll
    for (int n = 0; n < 4; ++n)
      bF[n] = *(const f16x8*)&Bs[(wc * 64 + n * 16 + fr) * 32 + fq * 8];
    #pragma unroll
    for (int m = 0; m < 4; ++m)
      #pragma unroll
      for (int n = 0; n < 4; ++n)
        acc[m][n] = __builtin_amdgcn_mfma_f32_16x16x32_f16(aF[m], bF[n], acc[m][n], 0, 0, 0);
  }

  __half* dst = (cb == 0) ? xhH : xtH;
  #pragma unroll
  for (int m = 0; m < 4; ++m) {
    const int rl0 = wr * 64 + m * 16 + fq * 4;
    #pragma unroll
    for (int r = 0; r < 4; ++r) {
      const int node = n0 + rl0 + r;
      if (node < N) {
        #pragma unroll
        for (int n = 0; n < 4; ++n)
          dst[(size_t)node * R_HID + wc * 64 + n * 16 + fr] = __float2half(acc[m][n][r]);
      }
    }
  }

  const float* aV1 = (cb == 0) ? ah1 : ah2;
  const float* aV2 = (cb == 0) ? at1 : at2;
  float avA[4], avB[4];
  #pragma unroll
  for (int n = 0; n < 4; ++n) {
    avA[n] = aV1[wc * 64 + n * 16 + fr];
    avB[n] = aV2[wc * 64 + n * 16 + fr];
  }
  #pragma unroll
  for (int m = 0; m < 4; ++m)
    #pragma unroll
    for (int r = 0; r < 4; ++r) {
      float vA = acc[m][0][r]*avA[0] + acc[m][1][r]*avA[1]
               + acc[m][2][r]*avA[2] + acc[m][3][r]*avA[3];
      float vB = acc[m][0][r]*avB[0] + acc[m][1][r]*avB[1]
               + acc[m][2][r]*avB[2] + acc[m][3][r]*avB[3];
      #pragma unroll
      for (int ofs = 1; ofs < 16; ofs <<= 1) {
        vA += __shfl_xor(vA, ofs, 16);
        vB += __shfl_xor(vB, ofs, 16);
      }
      if (fr == 0) {
        const int rl = wr * 64 + m * 16 + fq * 4 + r;
        sA[wc][rl] = vA;
        sB[wc][rl] = vB;
      }
    }
  __syncthreads();
  if (tid < 128 && n0 + tid < N) {
    float* o1 = (cb == 0) ? sh1 : sh2;
    float* o2 = (cb == 0) ? st1 : st2;
    o1[n0 + tid] = sA[0][tid] + sA[1][tid];
    o2[n0 + tid] = sB[0][tid] + sB[1][tid];
  }
}

// ================= K2: per-block LDS histograms over (rtile,chunk) bins =====
__global__ __launch_bounds__(256) void k2_hist(
    const int* __restrict__ ei, const int* __restrict__ rel,
    unsigned* __restrict__ bcH, unsigned* __restrict__ bcT, int E)
{
  __shared__ unsigned lcH[NBIN];
  __shared__ unsigned lcT[NBIN];
  const int tid = threadIdx.x;
  for (int j = tid; j < NBIN; j += 256) { lcH[j] = 0u; lcT[j] = 0u; }
  __syncthreads();
  for (int i = blockIdx.x * 256 + tid; i < E; i += NB * 256) {
    const int r = rel[i];
    atomicAdd(&lcH[(r >> 4) * NCH + (ei[i] >> CH_BITS)], 1u);
    atomicAdd(&lcT[(r >> 4) * NCH + (ei[E + i] >> CH_BITS)], 1u);
  }
  __syncthreads();
  for (int j = tid; j < NBIN; j += 256) {
    bcH[(size_t)blockIdx.x * NBIN + j] = lcH[j];
    bcT[(size_t)blockIdx.x * NBIN + j] = lcT[j];
  }
}

// ================= K3a: per-bin exclusive scan over NB block counts =========
__global__ __launch_bounds__(64) void k3a_scan(
    const unsigned* __restrict__ bcH, const unsigned* __restrict__ bcT,
    unsigned* __restrict__ preH, unsigned* __restrict__ preT,
    unsigned* __restrict__ cntH, unsigned* __restrict__ cntT)
{
  const int list = blockIdx.x / NBIN;
  const int bin  = blockIdx.x % NBIN;
  const unsigned* bc = list ? bcT : bcH;
  unsigned* pre = list ? preT : preH;
  const int lane = threadIdx.x;
  unsigned running = 0u;
  for (int b0 = 0; b0 < NB; b0 += 64) {
    const int b = b0 + lane;
    const unsigned v = bc[(size_t)b * NBIN + bin];
    unsigned inc = v;
    #pragma unroll
    for (int ofs = 1; ofs < 64; ofs <<= 1) {
      const unsigned nv = __shfl_up(inc, ofs, 64);
      if (lane >= ofs) inc += nv;
    }
    pre[(size_t)b * NBIN + bin] = running + inc - v;
    running += __shfl(inc, 63, 64);
  }
  if (lane == 0) (list ? cntT : cntH)[bin] = running;
}

// ================= K3b: scan bin totals -> offs =============================
__global__ __launch_bounds__(1024) void k3b_scan(
    const unsigned* __restrict__ cntH, const unsigned* __restrict__ cntT,
    unsigned* __restrict__ offsH, unsigned* __restrict__ offsT)
{
  __shared__ unsigned s[1024];
  const int t = threadIdx.x;
  for (int list = 0; list < 2; ++list) {
    const unsigned* cnt = list ? cntT : cntH;
    unsigned* offs = list ? offsT : offsH;
    s[t] = (t < NBIN) ? cnt[t] : 0u;
    __syncthreads();
    for (int ofs = 1; ofs < 1024; ofs <<= 1) {
      const unsigned add = (t >= ofs) ? s[t - ofs] : 0u;
      __syncthreads();
      s[t] += add;
      __syncthreads();
    }
    if (t == 0) offs[0] = 0u;
    if (t < NBIN) offs[t + 1] = s[t];
    __syncthreads();
  }
}

// ================= K4: counting-sort scatter (LDS ranks, no global atomics) =
// meta = { node(16b) | rl(4b)<<16 , w as f32 bits }
__global__ __launch_bounds__(256) void k4_scatter(
    const int* __restrict__ ei, const int* __restrict__ rel,
    const float* __restrict__ sh1, const float* __restrict__ sh2,
    const float* __restrict__ st1, const float* __restrict__ st2,
    const unsigned* __restrict__ offsH, const unsigned* __restrict__ offsT,
    const unsigned* __restrict__ preH, const unsigned* __restrict__ preT,
    uint2* __restrict__ metaH, uint2* __restrict__ metaT, int E)
{
  __shared__ unsigned lbH[NBIN];
  __shared__ unsigned lbT[NBIN];
  const int tid = threadIdx.x;
  for (int j = tid; j < NBIN; j += 256) {
    lbH[j] = offsH[j] + preH[(size_t)blockIdx.x * NBIN + j];
    lbT[j] = offsT[j] + preT[(size_t)blockIdx.x * NBIN + j];
  }
  __syncthreads();
  for (int i = blockIdx.x * 256 + tid; i < E; i += NB * 256) {
    const int h = ei[i], t = ei[E + i], r = rel[i];
    const float e1 = sh1[h] + sh2[t];
    const float e2 = st1[h] + st2[t];
    const float l1 = e1 >= 0.f ? e1 : 0.01f * e1;
    const float l2 = e2 >= 0.f ? e2 : 0.01f * e2;
    const unsigned pH = atomicAdd(&lbH[(r >> 4) * NCH + (h >> CH_BITS)], 1u);
    metaH[pH] = make_uint2((unsigned)h | ((unsigned)(r & 15) << 16),
                           __float_as_uint(expf(l1)));
    const unsigned pT = atomicAdd(&lbT[(r >> 4) * NCH + (t >> CH_BITS)], 1u);
    metaT[pT] = make_uint2((unsigned)t | ((unsigned)(r & 15) << 16),
                           __float_as_uint(expf(l2)));
  }
}

// ================= K5: gather-reduce into LDS rel-tile via ds_add_f32 =======
// bid -> (table, rtile, rep). 4 waves/block, each owns a contiguous slice of
// the chunk-sorted rtile range. Meta reads are wave-uniform (scalar loads);
// each lane covers 2 dims (half2 gather from L2-resident chunk slice);
// accumulation via LDS float atomics (2-way bank aliasing = free).
__global__ __launch_bounds__(256) void k5_reduce(
    const unsigned* __restrict__ offsH, const unsigned* __restrict__ offsT,
    const uint2* __restrict__ metaH, const uint2* __restrict__ metaT,
    const __half* __restrict__ xhH, const __half* __restrict__ xtH,
    float* __restrict__ part, float* __restrict__ partS)
{
  __shared__ float accC[RT * R_HID];
  __shared__ float accS[RT];

  const int tid  = threadIdx.x;
  const int lane = tid & 63;
  const int wv   = __builtin_amdgcn_readfirstlane(tid >> 6);  // scalar wave id
  const int bid  = blockIdx.x;
  const int table = bid / (NRT * REP);
  const int rem   = bid % (NRT * REP);
  const int rtile = rem / REP;
  const int rep   = rem % REP;

  for (int i = tid; i < RT * R_HID; i += 256) accC[i] = 0.f;
  if (tid < RT) accS[tid] = 0.f;
  __syncthreads();

  const unsigned* offs = table ? offsT : offsH;
  const uint2*    meta = table ? metaT : metaH;
  const __half*   xsrc = table ? xtH   : xhH;
  const __half*   xl   = xsrc + 2 * lane;       // lane's dim pair base

  const unsigned R0 = offs[rtile * NCH];
  const unsigned R1 = offs[rtile * NCH + NCH];
  const unsigned len = R1 - R0;
  const int q = rep * 4 + wv;                   // 0..63
  unsigned p        = R0 + (unsigned)(((unsigned long long)len * (unsigned)q) / QTOT);
  const unsigned pe = R0 + (unsigned)(((unsigned long long)len * (unsigned)(q + 1)) / QTOT);

#define PROC(MM) do { \
    const unsigned node = (MM).x & 0xFFFFu; \
    const unsigned rl   = (MM).x >> 16; \
    const float w = __uint_as_float((MM).y); \
    const float2 f = __half22float2(*(const __half2*)(xl + (size_t)node * R_HID)); \
    atomicAdd(&accC[rl * R_HID + 2 * lane],     w * f.x); \
    atomicAdd(&accC[rl * R_HID + 2 * lane + 1], w * f.y); \
    if (lane == 0) atomicAdd(&accS[rl], w); \
  } while (0)

  for (; p + 4 <= pe; p += 4) {
    const uint2 m0 = meta[p],     m1 = meta[p + 1];
    const uint2 m2 = meta[p + 2], m3 = meta[p + 3];
    PROC(m0); PROC(m1); PROC(m2); PROC(m3);
  }
  for (; p < pe; ++p) {
    const uint2 m = meta[p];
    PROC(m);
  }
#undef PROC

  __syncthreads();
  float* pd = part + (size_t)bid * (RT * R_HID);
  for (int i = tid; i < RT * R_HID; i += 256) pd[i] = accC[i];
  if (tid < RT) partS[bid * RT + tid] = accS[tid];
}

// ================= K6: reduce partials, finalize ============================
__global__ __launch_bounds__(128) void k6_final(
    const float* __restrict__ part, const float* __restrict__ partS,
    float* __restrict__ out)
{
  const int r = blockIdx.x;
  const int d = threadIdx.x;
  const int rtile = r >> 4, rl = r & 15;
  float oh = 0.f, ot = 0.f, s1 = 0.f, s2 = 0.f;
  #pragma unroll
  for (int rep = 0; rep < REP; ++rep) {
    const int pid0 = rtile * REP + rep;
    const int pid1 = NRT * REP + rtile * REP + rep;
    oh += part[(size_t)pid0 * (RT * R_HID) + rl * R_HID + d];
    ot += part[(size_t)pid1 * (RT * R_HID) + rl * R_HID + d];
    s1 += partS[pid0 * RT + rl];
    s2 += partS[pid1 * RT + rl];
  }
  out[r * R_HID + d] = oh / (s1 + EPSF) + ot / (s2 + EPSF);
}

extern "C" void kernel_launch(void* const* d_in, const int* in_sizes, int n_in,
                              void* d_out, int out_size, void* d_ws, size_t ws_size,
                              hipStream_t stream) {
  const float* xe  = (const float*)d_in[0];
  const int*   ei  = (const int*)d_in[1];
  const int*   rel = (const int*)d_in[2];
  const float* Wh  = (const float*)d_in[3];
  const float* Wt  = (const float*)d_in[4];
  const float* ah1 = (const float*)d_in[5];
  const float* ah2 = (const float*)d_in[6];
  const float* at1 = (const float*)d_in[7];
  const float* at2 = (const float*)d_in[8];
  const int N = in_sizes[0] / E_HID;
  const int E = in_sizes[2];

  char* w = (char*)d_ws;
  size_t o = 0;
  auto alloc = [&](size_t bytes) -> void* {
    void* p = w + o;
    o = (o + bytes + 255) & ~(size_t)255;
    return p;
  };
  __half* WcT = (__half*)alloc((size_t)E_HID * E_HID * 2);
  __half* xhH = (__half*)alloc((size_t)N * R_HID * 2);
  __half* xtH = (__half*)alloc((size_t)N * R_HID * 2);
  float* sh1 = (float*)alloc((size_t)N * 4);
  float* sh2 = (float*)alloc((size_t)N * 4);
  float* st1 = (float*)alloc((size_t)N * 4);
  float* st2 = (float*)alloc((size_t)N * 4);
  uint2* metaH = (uint2*)alloc((size_t)E * 8);
  uint2* metaT = (uint2*)alloc((size_t)E * 8);
  unsigned* bcH  = (unsigned*)alloc((size_t)NB * NBIN * 4);
  unsigned* bcT  = (unsigned*)alloc((size_t)NB * NBIN * 4);
  unsigned* preH = (unsigned*)alloc((size_t)NB * NBIN * 4);
  unsigned* preT = (unsigned*)alloc((size_t)NB * NBIN * 4);
  unsigned* cntH = (unsigned*)alloc((size_t)NBIN * 4);
  unsigned* cntT = (unsigned*)alloc((size_t)NBIN * 4);
  unsigned* offsH = (unsigned*)alloc((size_t)(NBIN + 1) * 4);
  unsigned* offsT = (unsigned*)alloc((size_t)(NBIN + 1) * 4);
  float* part  = (float*)alloc((size_t)G5 * RT * R_HID * 4);
  float* partS = (float*)alloc((size_t)G5 * RT * 4);

  const int nbm = (N + 127) >> 7;
  k0_prep<<<E_HID, 256, 0, stream>>>(Wh, Wt, WcT);
  k1_gemm<<<nbm * 2, 256, 0, stream>>>(xe, WcT, ah1, ah2, at1, at2,
                                       xhH, xtH, sh1, sh2, st1, st2, N);
  k2_hist<<<NB, 256, 0, stream>>>(ei, rel, bcH, bcT, E);
  k3a_scan<<<2 * NBIN, 64, 0, stream>>>(bcH, bcT, preH, preT, cntH, cntT);
  k3b_scan<<<1, 1024, 0, stream>>>(cntH, cntT, offsH, offsT);
  k4_scatter<<<NB, 256, 0, stream>>>(ei, rel, sh1, sh2, st1, st2,
                                     offsH, offsT, preH, preT,
                                     metaH, metaT, E);
  k5_reduce<<<G5, 256, 0, stream>>>(offsH, offsT, metaH, metaT, xhH, xtH,
                                    part, partS);
  k6_final<<<NREL, 128, 0, stream>>>(part, partS, (float*)d_out);
}

// Round 7
// 305.383 us; speedup vs baseline: 7.2946x; 7.2946x over previous
//
#include <hip/hip_runtime.h>
#include <hip/hip_fp16.h>
#include <cstdint>
#include <cstddef>

#define E_HID 256
#define R_HID 128
#define NREL  1000
#define EPSF  1e-16f
#define NB    256                 // blocks per list for edge passes (k2/k4)
#define CH_BITS 12
#define NCH   13                  // ceil(50000/4096) node chunks
#define NBIN  (NREL * NCH)        // 13000 bins per table (rel-major, chunk-minor)
#define SPLIT 2                   // blocks per (table, rel)
#define G5    (2 * NREL * SPLIT)  // 4000 blocks

typedef _Float16 f16x8 __attribute__((ext_vector_type(8)));
typedef float f32x4 __attribute__((ext_vector_type(4)));

struct alignas(16) h8 { __half2 a, b, c, d; };

// ================= K0: WcT[c][k] = fp16 of (c<128 ? Wh[k][c] : Wt[k][c-128])
__global__ __launch_bounds__(256) void k0_prep(
    const float* __restrict__ Wh, const float* __restrict__ Wt,
    __half* __restrict__ WcT)
{
  const int k = blockIdx.x;
  const int c = threadIdx.x;
  const float v = (c < R_HID) ? Wh[(size_t)k * R_HID + c]
                              : Wt[(size_t)k * R_HID + (c - R_HID)];
  WcT[(size_t)c * E_HID + k] = __float2half(v);
}

// ================= K1: MFMA fp16 GEMM (validated R3/R4/R6) ==================
__global__ __launch_bounds__(256) void k1_gemm(
    const float* __restrict__ xe, const __half* __restrict__ WcT,
    const float* __restrict__ ah1, const float* __restrict__ ah2,
    const float* __restrict__ at1, const float* __restrict__ at2,
    __half* __restrict__ xhH, __half* __restrict__ xtH,
    float* __restrict__ sh1, float* __restrict__ sh2,
    float* __restrict__ st1, float* __restrict__ st2, int N)
{
  __shared__ __half As[128 * 32];
  __shared__ __half Bs[128 * 32];
  __shared__ float sA[2][128];
  __shared__ float sB[2][128];

  const int tid  = threadIdx.x;
  const int lane = tid & 63;
  const int wid  = tid >> 6;
  const int wr = wid >> 1, wc = wid & 1;
  const int nbm = (N + 127) >> 7;
  const int mb = blockIdx.x % nbm;
  const int cb = blockIdx.x / nbm;
  const int n0 = mb * 128;

  f32x4 acc[4][4];
  #pragma unroll
  for (int m = 0; m < 4; ++m)
    #pragma unroll
    for (int n = 0; n < 4; ++n) acc[m][n] = (f32x4){0.f, 0.f, 0.f, 0.f};

  const int arow = tid >> 1, ah = tid & 1;
  const bool aok = (n0 + arow) < N;
  const float*  xsrc = xe + (size_t)(n0 + arow) * E_HID + ah * 16;
  const __half* bsrc = WcT + ((size_t)(cb * 128 + arow) << 8) + ah * 16;
  __half* Aw = &As[arow * 32 + ah * 16];
  __half* Bw = &Bs[arow * 32 + ah * 16];

  const int fr = lane & 15, fq = lane >> 4;

  for (int kt = 0; kt < 8; ++kt) {
    __syncthreads();
    float4 v0 = make_float4(0,0,0,0), v1 = v0, v2 = v0, v3 = v0;
    if (aok) {
      const float* s = xsrc + kt * 32;
      v0 = *(const float4*)(s);     v1 = *(const float4*)(s + 4);
      v2 = *(const float4*)(s + 8); v3 = *(const float4*)(s + 12);
    }
    h8 p0, p1;
    p0.a = __floats2half2_rn(v0.x, v0.y); p0.b = __floats2half2_rn(v0.z, v0.w);
    p0.c = __floats2half2_rn(v1.x, v1.y); p0.d = __floats2half2_rn(v1.z, v1.w);
    p1.a = __floats2half2_rn(v2.x, v2.y); p1.b = __floats2half2_rn(v2.z, v2.w);
    p1.c = __floats2half2_rn(v3.x, v3.y); p1.d = __floats2half2_rn(v3.z, v3.w);
    *(h8*)(Aw) = p0; *(h8*)(Aw + 8) = p1;
    float4 b0 = *(const float4*)(bsrc + kt * 32);
    float4 b1 = *(const float4*)(bsrc + kt * 32 + 8);
    *(float4*)(Bw) = b0; *(float4*)(Bw + 8) = b1;
    __syncthreads();
    f16x8 aF[4], bF[4];
    #pragma unroll
    for (int m = 0; m < 4; ++m)
      aF[m] = *(const f16x8*)&As[(wr * 64 + m * 16 + fr) * 32 + fq * 8];
    #pragma unroll
    for (int n = 0; n < 4; ++n)
      bF[n] = *(const f16x8*)&Bs[(wc * 64 + n * 16 + fr) * 32 + fq * 8];
    #pragma unroll
    for (int m = 0; m < 4; ++m)
      #pragma unroll
      for (int n = 0; n < 4; ++n)
        acc[m][n] = __builtin_amdgcn_mfma_f32_16x16x32_f16(aF[m], bF[n], acc[m][n], 0, 0, 0);
  }

  __half* dst = (cb == 0) ? xhH : xtH;
  #pragma unroll
  for (int m = 0; m < 4; ++m) {
    const int rl0 = wr * 64 + m * 16 + fq * 4;
    #pragma unroll
    for (int r = 0; r < 4; ++r) {
      const int node = n0 + rl0 + r;
      if (node < N) {
        #pragma unroll
        for (int n = 0; n < 4; ++n)
          dst[(size_t)node * R_HID + wc * 64 + n * 16 + fr] = __float2half(acc[m][n][r]);
      }
    }
  }

  const float* aV1 = (cb == 0) ? ah1 : ah2;
  const float* aV2 = (cb == 0) ? at1 : at2;
  float avA[4], avB[4];
  #pragma unroll
  for (int n = 0; n < 4; ++n) {
    avA[n] = aV1[wc * 64 + n * 16 + fr];
    avB[n] = aV2[wc * 64 + n * 16 + fr];
  }
  #pragma unroll
  for (int m = 0; m < 4; ++m)
    #pragma unroll
    for (int r = 0; r < 4; ++r) {
      float vA = acc[m][0][r]*avA[0] + acc[m][1][r]*avA[1]
               + acc[m][2][r]*avA[2] + acc[m][3][r]*avA[3];
      float vB = acc[m][0][r]*avB[0] + acc[m][1][r]*avB[1]
               + acc[m][2][r]*avB[2] + acc[m][3][r]*avB[3];
      #pragma unroll
      for (int ofs = 1; ofs < 16; ofs <<= 1) {
        vA += __shfl_xor(vA, ofs, 16);
        vB += __shfl_xor(vB, ofs, 16);
      }
      if (fr == 0) {
        const int rl = wr * 64 + m * 16 + fq * 4 + r;
        sA[wc][rl] = vA;
        sB[wc][rl] = vB;
      }
    }
  __syncthreads();
  if (tid < 128 && n0 + tid < N) {
    float* o1 = (cb == 0) ? sh1 : sh2;
    float* o2 = (cb == 0) ? st1 : st2;
    o1[n0 + tid] = sA[0][tid] + sA[1][tid];
    o2[n0 + tid] = sB[0][tid] + sB[1][tid];
  }
}

// ================= K2: per-block LDS histograms, (rel,chunk) bins ===========
// grid = 2*NB; block handles one list (0: h-nodes, 1: t-nodes).
__global__ __launch_bounds__(256) void k2_hist(
    const int* __restrict__ ei, const int* __restrict__ rel,
    unsigned short* __restrict__ bc, int E)
{
  __shared__ unsigned lc[NBIN];   // 52 KB
  const int tid  = threadIdx.x;
  const int list = blockIdx.x / NB;
  const int b    = blockIdx.x % NB;
  for (int j = tid; j < NBIN; j += 256) lc[j] = 0u;
  __syncthreads();
  const int* nodes = ei + (size_t)list * E;
  for (int i = b * 256 + tid; i < E; i += NB * 256)
    atomicAdd(&lc[rel[i] * NCH + (nodes[i] >> CH_BITS)], 1u);
  __syncthreads();
  unsigned short* dst = bc + ((size_t)(list * NB + b)) * NBIN;
  for (int j = tid; j < NBIN; j += 256) dst[j] = (unsigned short)lc[j];
}

// ================= K3a: per-bin exclusive scan over NB block counts =========
__global__ __launch_bounds__(64) void k3a_scan(
    const unsigned short* __restrict__ bc, unsigned short* __restrict__ pre,
    unsigned* __restrict__ cnt)
{
  const int list = blockIdx.x / NBIN;
  const int bin  = blockIdx.x % NBIN;
  const int lane = threadIdx.x;
  unsigned running = 0u;
  for (int b0 = 0; b0 < NB; b0 += 64) {
    const int b = b0 + lane;
    const size_t idx = ((size_t)(list * NB + b)) * NBIN + bin;
    const unsigned v = bc[idx];
    unsigned inc = v;
    #pragma unroll
    for (int ofs = 1; ofs < 64; ofs <<= 1) {
      const unsigned nv = __shfl_up(inc, ofs, 64);
      if (lane >= ofs) inc += nv;
    }
    pre[idx] = (unsigned short)(running + inc - v);
    running += __shfl(inc, 63, 64);
  }
  if (lane == 0) cnt[list * NBIN + bin] = running;
}

// ================= K3b: carry-scan of 13000 bin totals per list =============
__global__ __launch_bounds__(1024) void k3b_scan(
    const unsigned* __restrict__ cnt, unsigned* __restrict__ offs)
{
  __shared__ unsigned s[1024];
  const int t = threadIdx.x;
  for (int list = 0; list < 2; ++list) {
    const unsigned* c = cnt + (size_t)list * NBIN;
    unsigned* o = offs + (size_t)list * (NBIN + 1);
    unsigned carry = 0u;
    for (int base = 0; base < NBIN; base += 1024) {
      const int idx = base + t;
      const unsigned v = (idx < NBIN) ? c[idx] : 0u;
      s[t] = v;
      __syncthreads();
      for (int ofs = 1; ofs < 1024; ofs <<= 1) {
        const unsigned add = (t >= ofs) ? s[t - ofs] : 0u;
        __syncthreads();
        s[t] += add;
        __syncthreads();
      }
      if (idx < NBIN) o[idx] = carry + s[t] - v;
      carry += s[1023];
      __syncthreads();
    }
    if (t == 0) o[NBIN] = carry;
    __syncthreads();
  }
}

// ================= K4: counting-sort scatter (LDS ranks, one list/block) ====
// meta = { node (32b), w as f32 bits }
__global__ __launch_bounds__(256) void k4_scatter(
    const int* __restrict__ ei, const int* __restrict__ rel,
    const float* __restrict__ sh1, const float* __restrict__ sh2,
    const float* __restrict__ st1, const float* __restrict__ st2,
    const unsigned* __restrict__ offs, const unsigned short* __restrict__ pre,
    uint2* __restrict__ metaH, uint2* __restrict__ metaT, int E)
{
  __shared__ unsigned lb[NBIN];   // 52 KB
  const int tid  = threadIdx.x;
  const int list = blockIdx.x / NB;
  const int b    = blockIdx.x % NB;
  const unsigned* o = offs + (size_t)list * (NBIN + 1);
  const unsigned short* pr = pre + ((size_t)(list * NB + b)) * NBIN;
  for (int j = tid; j < NBIN; j += 256) lb[j] = o[j] + pr[j];
  __syncthreads();
  uint2* meta = list ? metaT : metaH;
  for (int i = b * 256 + tid; i < E; i += NB * 256) {
    const int h = ei[i], t = ei[E + i], r = rel[i];
    float e, node;
    int nd;
    if (list == 0) { e = sh1[h] + sh2[t]; nd = h; }
    else           { e = st1[h] + st2[t]; nd = t; }
    const float l = e >= 0.f ? e : 0.01f * e;
    const float w = expf(l);
    const unsigned pos = atomicAdd(&lb[r * NCH + (nd >> CH_BITS)], 1u);
    meta[pos] = make_uint2((unsigned)nd, __float_as_uint(w));
    (void)node;
  }
}

// ================= K5: register-accumulating gather-reduce ==================
// bid -> (list, rel, split). 4 waves/block; wave q of 8 owns slice [b0,b1) of
// rel's chunk-ordered edges. Uniform meta reads; lane covers dims {2l,2l+1};
// accumulate in 2 VGPRs; flush once via plain LDS stores -> per-block partial.
__global__ __launch_bounds__(256) void k5_reduce(
    const unsigned* __restrict__ offs,
    const uint2* __restrict__ metaH, const uint2* __restrict__ metaT,
    const __half* __restrict__ xhH, const __half* __restrict__ xtH,
    float* __restrict__ part, float* __restrict__ partS)
{
  __shared__ float accW[4][130];
  __shared__ float accSw[4];
  const int tid  = threadIdx.x;
  const int lane = tid & 63;
  const int wv   = __builtin_amdgcn_readfirstlane(tid >> 6);
  const int bid  = blockIdx.x;
  const int list = bid / (NREL * SPLIT);
  const int rr   = bid % (NREL * SPLIT);
  const int r    = rr / SPLIT;
  const int sp   = rr % SPLIT;

  const unsigned* o    = offs + (size_t)list * (NBIN + 1);
  const uint2*    meta = list ? metaT : metaH;
  const __half*   xsrc = list ? xtH   : xhH;
  const __half*   xl   = xsrc + 2 * lane;

  const unsigned R0 = o[r * NCH];
  const unsigned R1 = o[r * NCH + NCH];
  const unsigned len = R1 - R0;
  const int q = sp * 4 + wv;                    // 0..7
  unsigned p        = R0 + (unsigned)(((unsigned long long)len * (unsigned)q) >> 3);
  const unsigned pe = R0 + (unsigned)(((unsigned long long)len * (unsigned)(q + 1)) >> 3);

  float a0 = 0.f, a1 = 0.f, sw = 0.f;

  for (; p + 4 <= pe; p += 4) {
    const uint2 m0 = meta[p],     m1 = meta[p + 1];
    const uint2 m2 = meta[p + 2], m3 = meta[p + 3];
    const float2 f0 = __half22float2(*(const __half2*)(xl + ((size_t)m0.x << 7)));
    const float2 f1 = __half22float2(*(const __half2*)(xl + ((size_t)m1.x << 7)));
    const float2 f2 = __half22float2(*(const __half2*)(xl + ((size_t)m2.x << 7)));
    const float2 f3 = __half22float2(*(const __half2*)(xl + ((size_t)m3.x << 7)));
    const float w0 = __uint_as_float(m0.y), w1 = __uint_as_float(m1.y);
    const float w2 = __uint_as_float(m2.y), w3 = __uint_as_float(m3.y);
    a0 += w0 * f0.x; a1 += w0 * f0.y; sw += w0;
    a0 += w1 * f1.x; a1 += w1 * f1.y; sw += w1;
    a0 += w2 * f2.x; a1 += w2 * f2.y; sw += w2;
    a0 += w3 * f3.x; a1 += w3 * f3.y; sw += w3;
  }
  for (; p < pe; ++p) {
    const uint2 m = meta[p];
    const float2 f = __half22float2(*(const __half2*)(xl + ((size_t)m.x << 7)));
    const float w = __uint_as_float(m.y);
    a0 += w * f.x; a1 += w * f.y; sw += w;
  }

  accW[wv][2 * lane]     = a0;
  accW[wv][2 * lane + 1] = a1;
  if (lane == 0) accSw[wv] = sw;
  __syncthreads();
  if (tid < 128) {
    const float v = accW[0][tid] + accW[1][tid] + accW[2][tid] + accW[3][tid];
    part[(size_t)bid * R_HID + tid] = v;
  }
  if (tid == 0)
    partS[bid] = accSw[0] + accSw[1] + accSw[2] + accSw[3];
}

// ================= K6: reduce split partials, finalize ======================
__global__ __launch_bounds__(128) void k6_final(
    const float* __restrict__ part, const float* __restrict__ partS,
    float* __restrict__ out)
{
  const int r = blockIdx.x;
  const int d = threadIdx.x;
  float oh = 0.f, ot = 0.f, s1 = 0.f, s2 = 0.f;
  #pragma unroll
  for (int sp = 0; sp < SPLIT; ++sp) {
    const int pid0 = r * SPLIT + sp;
    const int pid1 = (NREL + r) * SPLIT + sp;
    oh += part[(size_t)pid0 * R_HID + d];
    ot += part[(size_t)pid1 * R_HID + d];
    s1 += partS[pid0];
    s2 += partS[pid1];
  }
  out[r * R_HID + d] = oh / (s1 + EPSF) + ot / (s2 + EPSF);
}

extern "C" void kernel_launch(void* const* d_in, const int* in_sizes, int n_in,
                              void* d_out, int out_size, void* d_ws, size_t ws_size,
                              hipStream_t stream) {
  const float* xe  = (const float*)d_in[0];
  const int*   ei  = (const int*)d_in[1];
  const int*   rel = (const int*)d_in[2];
  const float* Wh  = (const float*)d_in[3];
  const float* Wt  = (const float*)d_in[4];
  const float* ah1 = (const float*)d_in[5];
  const float* ah2 = (const float*)d_in[6];
  const float* at1 = (const float*)d_in[7];
  const float* at2 = (const float*)d_in[8];
  const int N = in_sizes[0] / E_HID;
  const int E = in_sizes[2];

  char* w = (char*)d_ws;
  size_t o = 0;
  auto alloc = [&](size_t bytes) -> void* {
    void* p = w + o;
    o = (o + bytes + 255) & ~(size_t)255;
    return p;
  };
  __half* WcT = (__half*)alloc((size_t)E_HID * E_HID * 2);
  __half* xhH = (__half*)alloc((size_t)N * R_HID * 2);
  __half* xtH = (__half*)alloc((size_t)N * R_HID * 2);
  float* sh1 = (float*)alloc((size_t)N * 4);
  float* sh2 = (float*)alloc((size_t)N * 4);
  float* st1 = (float*)alloc((size_t)N * 4);
  float* st2 = (float*)alloc((size_t)N * 4);
  uint2* metaH = (uint2*)alloc((size_t)E * 8);
  uint2* metaT = (uint2*)alloc((size_t)E * 8);
  unsigned short* bc  = (unsigned short*)alloc((size_t)2 * NB * NBIN * 2);
  unsigned short* pre = (unsigned short*)alloc((size_t)2 * NB * NBIN * 2);
  unsigned* cnt  = (unsigned*)alloc((size_t)2 * NBIN * 4);
  unsigned* offs = (unsigned*)alloc((size_t)2 * (NBIN + 1) * 4);
  float* part  = (float*)alloc((size_t)G5 * R_HID * 4);
  float* partS = (float*)alloc((size_t)G5 * 4);

  const int nbm = (N + 127) >> 7;
  k0_prep<<<E_HID, 256, 0, stream>>>(Wh, Wt, WcT);
  k1_gemm<<<nbm * 2, 256, 0, stream>>>(xe, WcT, ah1, ah2, at1, at2,
                                       xhH, xtH, sh1, sh2, st1, st2, N);
  k2_hist<<<2 * NB, 256, 0, stream>>>(ei, rel, bc, E);
  k3a_scan<<<2 * NBIN, 64, 0, stream>>>(bc, pre, cnt);
  k3b_scan<<<1, 1024, 0, stream>>>(cnt, offs);
  k4_scatter<<<2 * NB, 256, 0, stream>>>(ei, rel, sh1, sh2, st1, st2,
                                         offs, pre, metaH, metaT, E);
  k5_reduce<<<G5, 256, 0, stream>>>(offs, metaH, metaT, xhH, xtH, part, partS);
  k6_final<<<NREL, 128, 0, stream>>>(part, partS, (float*)d_out);
}